// Round 4
// baseline (390.300 us; speedup 1.0000x reference)
//
#include <hip/hip_runtime.h>
#include <math.h>

#define NN 768
#define SD 384
#define HH 12

#define W_L 0.57735026918962576f   /* sqrt(1/3) */
#define W_C 0.23570226039551584f   /* sqrt(2/36) */

typedef __attribute__((ext_vector_type(8))) short short8;
typedef __attribute__((ext_vector_type(4))) float floatx4;
typedef unsigned short ushort_t;
typedef unsigned int uint_t;

__device__ __forceinline__ float wave_max(float v){ for(int o=32;o;o>>=1) v=fmaxf(v,__shfl_xor(v,o)); return v; }
__device__ __forceinline__ float wave_sum(float v){ for(int o=32;o;o>>=1) v+=__shfl_xor(v,o); return v; }

static __device__ __forceinline__ ushort_t f2bf(float f) {
  union { float f; uint_t u; } v; v.f = f;
  uint_t r = (v.u + 0x7FFFu + ((v.u >> 16) & 1u)) >> 16;
  return (ushort_t)r;
}
static __device__ __forceinline__ float bf2f(ushort_t u) {
  union { uint_t u; float f; } v; v.u = ((uint_t)u) << 16; return v.f;
}

// ---------------- K1a: raw = single @ [Wqkv|Wqk|Wvp]  (768x1152x384) ----
__global__ __launch_bounds__(256) void k1a_gemm(
    const float* __restrict__ single, const float* __restrict__ Wqkv,
    const float* __restrict__ Wqk, const float* __restrict__ Wvp,
    float* __restrict__ raw)
{
  __shared__ float Al[64][17];
  __shared__ float Bl[16][68];
  const int tid = threadIdx.x;
  const int bm = blockIdx.x / 18, bn = blockIdx.x % 18;
  const int tr = tid >> 4, tc = tid & 15;

  const int bcol = bn*64 + (tid & 15)*4;
  const float* Wsrc; int wstride;
  if (bcol < 576)      { Wsrc = Wqkv + bcol;        wstride = 576; }
  else if (bcol < 864) { Wsrc = Wqk  + (bcol-576);  wstride = 288; }
  else                 { Wsrc = Wvp  + (bcol-864);  wstride = 288; }
  const int brow = tid >> 4;
  const int ar = tid >> 2, ac = (tid & 3)*4;

  float4 acc0 = {0,0,0,0}, acc1 = {0,0,0,0}, acc2 = {0,0,0,0}, acc3 = {0,0,0,0};

  for (int kc = 0; kc < 24; ++kc) {
    __syncthreads();
    *(float4*)&Al[ar][ac] = *(const float4*)(single + (size_t)(bm*64+ar)*SD + kc*16 + ac);
    *(float4*)&Bl[brow][(tid&15)*4] = *(const float4*)(Wsrc + (size_t)(kc*16+brow)*wstride);
    __syncthreads();
    #pragma unroll
    for (int kk = 0; kk < 16; ++kk) {
      float a0 = Al[tr*4+0][kk], a1 = Al[tr*4+1][kk], a2 = Al[tr*4+2][kk], a3 = Al[tr*4+3][kk];
      float4 bv = *(float4*)&Bl[kk][tc*4];
      acc0.x += a0*bv.x; acc0.y += a0*bv.y; acc0.z += a0*bv.z; acc0.w += a0*bv.w;
      acc1.x += a1*bv.x; acc1.y += a1*bv.y; acc1.z += a1*bv.z; acc1.w += a1*bv.w;
      acc2.x += a2*bv.x; acc2.y += a2*bv.y; acc2.z += a2*bv.z; acc2.w += a2*bv.w;
      acc3.x += a3*bv.x; acc3.y += a3*bv.y; acc3.z += a3*bv.z; acc3.w += a3*bv.w;
    }
  }
  float* o = raw + (size_t)(bm*64 + tr*4)*1152 + bn*64 + tc*4;
  *(float4*)(o)            = acc0;
  *(float4*)(o + 1152)     = acc1;
  *(float4*)(o + 2*1152)   = acc2;
  *(float4*)(o + 3*1152)   = acc3;
}

// ---------------- K1b: pack Q~ (f32), K~ (bf16), vvb (bf16) + frames ----
__global__ __launch_bounds__(256) void k1b_pack(
    const float* __restrict__ raw_g, const float* __restrict__ rot,
    const float* __restrict__ trans, const float* __restrict__ gamma,
    float* __restrict__ Qt, ushort_t* __restrict__ Ktb, ushort_t* __restrict__ vvb)
{
  __shared__ float raw[4][1152];
  __shared__ float gbuf[4][16][HH][3];
  const int tid = threadIdx.x;
  const int i0 = blockIdx.x * 4;

  for (int s = tid; s < 4*288; s += 256) {
    int r = s / 288, q = s % 288;
    *(float4*)(&raw[r][q*4]) = *(const float4*)(raw_g + (size_t)(i0+r)*1152 + q*4);
  }
  __syncthreads();

  for (int s = tid; s < 4*576; s += 256) {
    int r = s / 576, cc = s % 576;
    int d = (cc % 192) / HH, h = cc % HH;
    int i = i0 + r;
    float val = raw[r][cc];
    if (cc < 192)       Qt[(size_t)i*384 + h*32 + d] = 0.25f*W_L*val;
    else if (cc < 384)  Ktb[(size_t)i*384 + h*32 + d] = f2bf(val);
    else                vvb[(size_t)i*480 + h*40 + d] = f2bf(val);
  }
  for (int s = tid; s < 768; s += 256) {
    int r = s / 192, rem = s % 192;
    int slot = rem / HH, h = rem % HH;
    int i = i0 + r;
    int base;
    if (slot < 4) base = 576 + slot*36;
    else if (slot < 8) base = 720 + (slot-4)*36;
    else base = 864 + (slot-8)*36;
    float x0 = raw[r][base + 0*12 + h];
    float x1 = raw[r][base + 1*12 + h];
    float x2 = raw[r][base + 2*12 + h];
    const float* R = rot + (size_t)i*9;
    const float* T = trans + (size_t)i*3;
    float g0 = R[0]*x0 + R[1]*x1 + R[2]*x2 + T[0];
    float g1 = R[3]*x0 + R[4]*x1 + R[5]*x2 + T[1];
    float g2 = R[6]*x0 + R[7]*x1 + R[8]*x2 + T[2];
    gbuf[r][slot][h][0]=g0; gbuf[r][slot][h][1]=g1; gbuf[r][slot][h][2]=g2;
    if (slot < 4) {
      float sc2 = 2.0f*W_L*(gamma[h]*W_C*0.5f);
      float* q = Qt + (size_t)i*384 + h*32 + 16 + slot*3;
      q[0]=sc2*g0; q[1]=sc2*g1; q[2]=sc2*g2;
    } else if (slot < 8) {
      ushort_t* k = Ktb + (size_t)i*384 + h*32 + 16 + (slot-4)*3;
      k[0]=f2bf(g0); k[1]=f2bf(g1); k[2]=f2bf(g2);
    } else {
      ushort_t* vp = vvb + (size_t)i*480 + h*40 + 16 + (slot-8)*3;
      vp[0]=f2bf(g0); vp[1]=f2bf(g1); vp[2]=f2bf(g2);
    }
  }
  __syncthreads();
  for (int s = tid; s < 96; s += 256) {
    int r = s / 24, rem = s % 24;
    int h = rem / 2, qk = rem % 2;
    int i = i0 + r;
    float sum = 0;
    int b0 = qk ? 4 : 0;
    for (int p = 0; p < 4; ++p)
      for (int t = 0; t < 3; ++t) { float g = gbuf[r][b0+p][h][t]; sum += g*g; }
    float sc = gamma[h]*W_C*0.5f;
    if (qk == 0) {
      float* q = Qt + (size_t)i*384 + h*32;
      q[28] = -W_L*sc; q[29] = -W_L*sc*sum; q[30] = 0.f; q[31] = 0.f;
    } else {
      ushort_t* k = Ktb + (size_t)i*384 + h*32;
      k[28] = f2bf(sum); k[29] = f2bf(1.f); k[30] = 0; k[31] = 0;
    }
  }
}

// ---------------- K2a: logits L[i,h,j] (MFMA, one barrier) --------------
__global__ __launch_bounds__(256) void k2a_logits(
    const float* __restrict__ pair, const float* __restrict__ Wb,
    const float* __restrict__ Qt, const ushort_t* __restrict__ Ktb,
    float* __restrict__ L)
{
  __shared__ ushort_t Tj[64*136];
  __shared__ ushort_t WbT[16*136];
  __shared__ float Qrow[384];
  const int tid = threadIdx.x;
  const int i = blockIdx.x / 12;
  const int j0 = (blockIdx.x % 12) * 64;
  const int lane = tid & 63;
  const int w = tid >> 6;
  const int co = lane & 15, gg = lane >> 4;

  for (int s = tid; s < 1536; s += 256) {
    int z = s / 12, h = s % 12;
    WbT[h*136 + z] = f2bf(W_L * Wb[s]);
  }
  for (int s = tid; s < 544; s += 256) WbT[1632 + s] = 0;
  for (int s = tid; s < 384; s += 256) Qrow[s] = Qt[(size_t)i*384 + s];

  const float* src = pair + ((size_t)i*NN + j0)*128;
  #pragma unroll
  for (int k = 0; k < 8; ++k) {
    int f = tid + k*256;
    int row = f >> 5, zq = f & 31;
    float4 v = *(const float4*)(src + (size_t)row*128 + zq*4);
    uint_t u0 = ((uint_t)f2bf(v.y) << 16) | f2bf(v.x);
    uint_t u1 = ((uint_t)f2bf(v.w) << 16) | f2bf(v.z);
    uint_t* d = (uint_t*)&Tj[row*136 + zq*4];
    d[0] = u0; d[1] = u1;
  }
  __syncthreads();

  short8 z8, myQ, wb[4];
  #pragma unroll
  for (int s = 0; s < 8; ++s) z8[s] = 0;
  #pragma unroll
  for (int s = 0; s < 8; ++s)
    myQ[s] = (co < 12) ? (short)f2bf(Qrow[co*32 + gg*8 + s]) : (short)0;
  #pragma unroll
  for (int kt = 0; kt < 4; ++kt)
    wb[kt] = *(const short8*)&WbT[co*136 + kt*32 + gg*8];

  const int jb = w*16;
  floatx4 D; D[0]=0.f; D[1]=0.f; D[2]=0.f; D[3]=0.f;
  #pragma unroll
  for (int kt = 0; kt < 4; ++kt) {
    short8 a = *(const short8*)&Tj[(jb+co)*136 + kt*32 + gg*8];
    D = __builtin_amdgcn_mfma_f32_16x16x32_bf16(a, wb[kt], D, 0, 0, 0);
  }
  const ushort_t* kr = Ktb + (size_t)(j0 + jb + co)*384;
  #pragma unroll
  for (int kt = 0; kt < 12; ++kt) {
    short8 a = *(const short8*)(kr + kt*32 + gg*8);
    short8 b = (co == kt) ? myQ : z8;
    D = __builtin_amdgcn_mfma_f32_16x16x32_bf16(a, b, D, 0, 0, 0);
  }
  if (co < 12) {
    float4 st = {D[0], D[1], D[2], D[3]};
    *(float4*)(L + ((size_t)i*12 + co)*768 + j0 + jb + gg*4) = st;
  }
}

// ---------------- K2b: softmax + out_pair^T (MFMA) ----------------------
__global__ __launch_bounds__(256) void k2b_pairout(
    const float* __restrict__ pair, float* __restrict__ L,
    float* __restrict__ C2)
{
  __shared__ ushort_t PTb[24*16*32];    // [tile][h16][j32] bf16 a
  __shared__ ushort_t Tz[32*134];       // [j32][z128+pad] bf16 pair tile
  const int tid = threadIdx.x;
  const int i = (NN - 1) - blockIdx.x;  // reverse order for L3 reuse
  const int lane = tid & 63;
  const int w = tid >> 6;
  const int co = lane & 15, gg = lane >> 4;

  // ---- softmax from global L (L2-hot), write bf16 a ----
  float* Lr = L + (size_t)i*12*768;
  ushort_t* abr = (ushort_t*)Lr;        // in-place bf16 a over own L row
  const int ln = lane;
  {
    const int wv = w;
    #pragma unroll 1
    for (int m = 0; m < 3; ++m) {
      int h = wv + 4*m;
      const float* row = Lr + (size_t)h*768;
      float mx = -1e30f;
      for (int jj = ln; jj < 768; jj += 64) mx = fmaxf(mx, row[jj]);
      mx = wave_max(mx);
      float sm = 0.f;
      float ev[12];
      #pragma unroll
      for (int k = 0; k < 12; ++k) {
        float e = __expf(row[ln + 64*k] - mx);
        ev[k] = e; sm += e;
      }
      sm = wave_sum(sm);
      float inv = 1.0f / sm;
      #pragma unroll
      for (int k = 0; k < 12; ++k) {
        int jj = ln + 64*k;
        ushort_t a = f2bf(ev[k]*inv);
        PTb[(jj >> 5)*512 + h*32 + (jj & 31)] = a;
      }
      // write ab AFTER exp values computed (row no longer needed)
      #pragma unroll
      for (int k = 0; k < 12; ++k) {
        int jj = ln + 64*k;
        abr[h*768 + jj] = f2bf(ev[k]*inv);
      }
    }
  }
  __syncthreads();

  // ---- out_pair^T accumulation over 24 j-tiles ----
  floatx4 accZ[2];
  #pragma unroll
  for (int u = 0; u < 2; ++u) { accZ[u][0]=0.f; accZ[u][1]=0.f; accZ[u][2]=0.f; accZ[u][3]=0.f; }

  const int srow = tid >> 5, szq = tid & 31;   // staging coords (x8 via +256)
  const float* psrc = pair + (size_t)i*NN*128;

  float4 pr[4];
  #pragma unroll
  for (int k = 0; k < 4; ++k) {
    int f = tid + k*256;
    int row = f >> 5, zq = f & 31;
    pr[k] = *(const float4*)(psrc + (size_t)row*128 + zq*4);
  }

  #pragma unroll 1
  for (int t = 0; t < 24; ++t) {
    // write current tile regs -> Tz
    #pragma unroll
    for (int k = 0; k < 4; ++k) {
      int f = tid + k*256;
      int row = f >> 5, zq = f & 31;
      uint_t u0 = ((uint_t)f2bf(pr[k].y) << 16) | f2bf(pr[k].x);
      uint_t u1 = ((uint_t)f2bf(pr[k].w) << 16) | f2bf(pr[k].z);
      uint_t* d = (uint_t*)Tz;
      d[row*67 + zq*2]     = u0;
      d[row*67 + zq*2 + 1] = u1;
    }
    __syncthreads();
    // prefetch next tile
    if (t < 23) {
      const float* sn = psrc + (size_t)(t+1)*32*128;
      #pragma unroll
      for (int k = 0; k < 4; ++k) {
        int f = tid + k*256;
        int row = f >> 5, zq = f & 31;
        pr[k] = *(const float4*)(sn + (size_t)row*128 + zq*4);
      }
    }
    // MFMA: out_pairT[h][z] += P[h][j] * T[j][z]
    short8 aP = *(const short8*)&PTb[t*512 + co*32 + gg*8];
    #pragma unroll
    for (int u = 0; u < 2; ++u) {
      const int n = w*2 + u;
      short8 bT;
      #pragma unroll
      for (int e = 0; e < 8; ++e)
        bT[e] = (short)Tz[(gg*8 + e)*134 + n*16 + co];
      accZ[u] = __builtin_amdgcn_mfma_f32_16x16x32_bf16(aP, bT, accZ[u], 0, 0, 0);
    }
    __syncthreads();
  }

  // store out_pair: C2[i*2112 + z*12 + h]
  float* o = C2 + (size_t)i*2112;
  #pragma unroll
  for (int u = 0; u < 2; ++u) {
    const int n = w*2 + u;
    #pragma unroll
    for (int r = 0; r < 4; ++r) {
      int h = gg*4 + r;
      if (h < 12) o[(n*16 + co)*12 + h] = accZ[u][r];
    }
  }
}

// ---------------- K4: out_value + points + norms ------------------------
__global__ __launch_bounds__(256) void k4_value_points(
    const float* __restrict__ L, const ushort_t* __restrict__ vvb,
    const float* __restrict__ rot, const float* __restrict__ trans,
    float* __restrict__ C2)
{
  __shared__ ushort_t abl[12*768];
  __shared__ ushort_t vt[32*488];
  __shared__ float oacc[480];
  const int tid = threadIdx.x;
  const int i = blockIdx.x;
  const ushort_t* abr = (const ushort_t*)(L + (size_t)i*12*768);

  for (int s = tid; s < 4608; s += 256)
    ((uint_t*)abl)[s] = ((const uint_t*)abr)[s];

  const int h = tid / 20, c2 = tid % 20;   // active if tid < 240
  float acc0 = 0.f, acc1 = 0.f;

  #pragma unroll 1
  for (int t = 0; t < 24; ++t) {
    __syncthreads();
    const ushort_t* src = vvb + (size_t)t*32*480;
    for (int s = tid; s < 1920; s += 256) {
      int row = s / 60, cq = s % 60;
      *(float4*)&vt[row*488 + cq*8] = *(const float4*)(src + (size_t)row*480 + cq*8);
    }
    __syncthreads();
    if (tid < 240) {
      const int j0 = t*32;
      #pragma unroll 4
      for (int jj = 0; jj < 32; ++jj) {
        float a = bf2f(abl[h*768 + j0 + jj]);
        uint_t pv = *(const uint_t*)&vt[jj*488 + h*40 + c2*2];
        acc0 += a * bf2f((ushort_t)(pv & 0xffffu));
        acc1 += a * bf2f((ushort_t)(pv >> 16));
      }
    }
  }
  __syncthreads();
  if (tid < 240) {
    oacc[h*40 + c2*2]     = acc0;
    oacc[h*40 + c2*2 + 1] = acc1;
  }
  __syncthreads();

  if (tid < 96) {
    const int pp = tid / 12, hh = tid % 12;
    const float* R = rot + (size_t)i*9;
    const float* T = trans + (size_t)i*3;
    float x0 = oacc[hh*40+16+pp*3+0] - T[0];
    float x1 = oacc[hh*40+16+pp*3+1] - T[1];
    float x2 = oacc[hh*40+16+pp*3+2] - T[2];
    float y0 = R[0]*x0 + R[3]*x1 + R[6]*x2;
    float y1 = R[1]*x0 + R[4]*x1 + R[7]*x2;
    float y2 = R[2]*x0 + R[5]*x1 + R[8]*x2;
    float* o = C2 + (size_t)i*2112;
    o[1728 + pp*36 + hh*3 + 0] = y0;
    o[1728 + pp*36 + hh*3 + 1] = y1;
    o[1728 + pp*36 + hh*3 + 2] = y2;
    o[2016 + pp*12 + hh] = sqrtf(y0*y0 + y1*y1 + y2*y2);
  } else if (tid >= 96 && tid < 288) {
    const int c = tid - 96;
    if (c < 192) {
      int d = c / 12, hh = c % 12;
      C2[(size_t)i*2112 + 1536 + d*12 + hh] = oacc[hh*40 + d];
    }
  }
}

// ---------------- K5: final GEMM 768x2112 @ 2112x384 + bias -------------
__global__ __launch_bounds__(256) void k5_out(
    const float* __restrict__ C2, const float* __restrict__ Wout,
    const float* __restrict__ bout, float* __restrict__ out)
{
  __shared__ float Al[32*68];
  __shared__ float Bl[64*36];
  const int tid = threadIdx.x;
  const int bm = blockIdx.x / 12, bn = blockIdx.x % 12;
  const int tr = tid / 16, tc = tid % 16;
  float acc00=0, acc01=0, acc10=0, acc11=0;
  for (int kc = 0; kc < 33; ++kc) {
    __syncthreads();
    for (int s = tid; s < 512; s += 256) {
      int row = s / 16, kq = s % 16;
      *(float4*)(&Al[row*68 + kq*4]) =
        *(const float4*)(C2 + (size_t)(bm*32+row)*2112 + kc*64 + kq*4);
    }
    for (int s = tid; s < 512; s += 256) {
      int kk = s / 8, cq = s % 8;
      *(float4*)(&Bl[kk*36 + cq*4]) =
        *(const float4*)(Wout + (size_t)(kc*64+kk)*384 + bn*32 + cq*4);
    }
    __syncthreads();
    for (int kk = 0; kk < 64; ++kk) {
      float a0 = Al[(tr*2)*68 + kk], a1 = Al[(tr*2+1)*68 + kk];
      float b0 = Bl[kk*36 + tc*2], b1 = Bl[kk*36 + tc*2 + 1];
      acc00 += a0*b0; acc01 += a0*b1;
      acc10 += a1*b0; acc11 += a1*b1;
    }
  }
  int r0 = bm*32 + tr*2, c0 = bn*32 + tc*2;
  out[(size_t)r0*384 + c0]       = acc00 + bout[c0];
  out[(size_t)r0*384 + c0+1]     = acc01 + bout[c0+1];
  out[(size_t)(r0+1)*384 + c0]   = acc10 + bout[c0];
  out[(size_t)(r0+1)*384 + c0+1] = acc11 + bout[c0+1];
}

extern "C" void kernel_launch(void* const* d_in, const int* in_sizes, int n_in,
                              void* d_out, int out_size, void* d_ws, size_t ws_size,
                              hipStream_t stream)
{
  const float* single = (const float*)d_in[0];
  const float* pair   = (const float*)d_in[1];
  const float* rot    = (const float*)d_in[2];
  const float* trans  = (const float*)d_in[3];
  const float* Wqkv   = (const float*)d_in[4];
  const float* Wb     = (const float*)d_in[5];
  const float* Wqk    = (const float*)d_in[6];
  const float* Wvp    = (const float*)d_in[7];
  const float* gamma  = (const float*)d_in[8];
  const float* Wout   = (const float*)d_in[9];
  const float* bout   = (const float*)d_in[10];

  float* ws   = (float*)d_ws;
  float* raw  = ws;                                   // 768*1152
  float* Qt   = raw + (size_t)768*1152;               // 768*384
  float* C2   = Qt  + (size_t)768*384;                // 768*2112
  float* L    = C2  + (size_t)768*2112;               // 768*12*768
  ushort_t* Ktb = (ushort_t*)(L + (size_t)768*12*768); // 768*384 bf16
  ushort_t* vvb = Ktb + (size_t)768*384;               // 768*480 bf16
  float* out  = (float*)d_out;

  k1a_gemm<<<dim3(216), dim3(256), 0, stream>>>(single, Wqkv, Wqk, Wvp, raw);
  k1b_pack<<<dim3(192), dim3(256), 0, stream>>>(raw, rot, trans, gamma, Qt, Ktb, vvb);
  k2a_logits<<<dim3(9216), dim3(256), 0, stream>>>(pair, Wb, Qt, Ktb, L);
  k2b_pairout<<<dim3(768), dim3(256), 0, stream>>>(pair, L, C2);
  k4_value_points<<<dim3(768), dim3(256), 0, stream>>>(L, vvb, rot, trans, C2);
  k5_out<<<dim3(288), dim3(256), 0, stream>>>(C2, Wout, bout, out);
}

// Round 5
// 320.007 us; speedup vs baseline: 1.2197x; 1.2197x over previous
//
#include <hip/hip_runtime.h>
#include <math.h>

#define NN 768
#define SD 384
#define HH 12

#define W_L 0.57735026918962576f   /* sqrt(1/3) */
#define W_C 0.23570226039551584f   /* sqrt(2/36) */

typedef __attribute__((ext_vector_type(8))) short short8;
typedef __attribute__((ext_vector_type(4))) short short4_t;
typedef __attribute__((ext_vector_type(4))) float floatx4;
typedef unsigned short ushort_t;
typedef unsigned int uint_t;

__device__ __forceinline__ float wave_max(float v){ for(int o=32;o;o>>=1) v=fmaxf(v,__shfl_xor(v,o)); return v; }
__device__ __forceinline__ float wave_sum(float v){ for(int o=32;o;o>>=1) v+=__shfl_xor(v,o); return v; }

static __device__ __forceinline__ ushort_t f2bf(float f) {
  union { float f; uint_t u; } v; v.f = f;
  uint_t r = (v.u + 0x7FFFu + ((v.u >> 16) & 1u)) >> 16;
  return (ushort_t)r;
}

// ---------------- K1a: raw = single @ [Wqkv|Wqk|Wvp]  (768x1152x384) ----
__global__ __launch_bounds__(256) void k1a_gemm(
    const float* __restrict__ single, const float* __restrict__ Wqkv,
    const float* __restrict__ Wqk, const float* __restrict__ Wvp,
    float* __restrict__ raw)
{
  __shared__ float Al[64][17];
  __shared__ float Bl[16][68];
  const int tid = threadIdx.x;
  const int bm = blockIdx.x / 18, bn = blockIdx.x % 18;
  const int tr = tid >> 4, tc = tid & 15;

  const int bcol = bn*64 + (tid & 15)*4;
  const float* Wsrc; int wstride;
  if (bcol < 576)      { Wsrc = Wqkv + bcol;        wstride = 576; }
  else if (bcol < 864) { Wsrc = Wqk  + (bcol-576);  wstride = 288; }
  else                 { Wsrc = Wvp  + (bcol-864);  wstride = 288; }
  const int brow = tid >> 4;
  const int ar = tid >> 2, ac = (tid & 3)*4;

  float4 acc0 = {0,0,0,0}, acc1 = {0,0,0,0}, acc2 = {0,0,0,0}, acc3 = {0,0,0,0};

  for (int kc = 0; kc < 24; ++kc) {
    __syncthreads();
    *(float4*)&Al[ar][ac] = *(const float4*)(single + (size_t)(bm*64+ar)*SD + kc*16 + ac);
    *(float4*)&Bl[brow][(tid&15)*4] = *(const float4*)(Wsrc + (size_t)(kc*16+brow)*wstride);
    __syncthreads();
    #pragma unroll
    for (int kk = 0; kk < 16; ++kk) {
      float a0 = Al[tr*4+0][kk], a1 = Al[tr*4+1][kk], a2 = Al[tr*4+2][kk], a3 = Al[tr*4+3][kk];
      float4 bv = *(float4*)&Bl[kk][tc*4];
      acc0.x += a0*bv.x; acc0.y += a0*bv.y; acc0.z += a0*bv.z; acc0.w += a0*bv.w;
      acc1.x += a1*bv.x; acc1.y += a1*bv.y; acc1.z += a1*bv.z; acc1.w += a1*bv.w;
      acc2.x += a2*bv.x; acc2.y += a2*bv.y; acc2.z += a2*bv.z; acc2.w += a2*bv.w;
      acc3.x += a3*bv.x; acc3.y += a3*bv.y; acc3.z += a3*bv.z; acc3.w += a3*bv.w;
    }
  }
  float* o = raw + (size_t)(bm*64 + tr*4)*1152 + bn*64 + tc*4;
  *(float4*)(o)            = acc0;
  *(float4*)(o + 1152)     = acc1;
  *(float4*)(o + 2*1152)   = acc2;
  *(float4*)(o + 3*1152)   = acc3;
}

// ---------------- K1b: pack Q~ (f32), K~ (bf16), vvT (bf16) + frames ----
__global__ __launch_bounds__(256) void k1b_pack(
    const float* __restrict__ raw_g, const float* __restrict__ rot,
    const float* __restrict__ trans, const float* __restrict__ gamma,
    float* __restrict__ Qt, ushort_t* __restrict__ Ktb, ushort_t* __restrict__ vvT)
{
  __shared__ float raw[4][1152];
  __shared__ float gbuf[4][16][HH][3];
  const int tid = threadIdx.x;
  const int i0 = blockIdx.x * 4;

  for (int s = tid; s < 4*288; s += 256) {
    int r = s / 288, q = s % 288;
    *(float4*)(&raw[r][q*4]) = *(const float4*)(raw_g + (size_t)(i0+r)*1152 + q*4);
  }
  __syncthreads();

  for (int s = tid; s < 4*576; s += 256) {
    int r = s / 576, cc = s % 576;
    int d = (cc % 192) / HH, h = cc % HH;
    int i = i0 + r;
    float val = raw[r][cc];
    if (cc < 192)       Qt[(size_t)i*384 + h*32 + d] = 0.25f*W_L*val;
    else if (cc < 384)  Ktb[(size_t)i*384 + h*32 + d] = f2bf(val);
    else                vvT[(size_t)(h*40 + d)*768 + i] = f2bf(val);
  }
  for (int s = tid; s < 768; s += 256) {
    int r = s / 192, rem = s % 192;
    int slot = rem / HH, h = rem % HH;
    int i = i0 + r;
    int base;
    if (slot < 4) base = 576 + slot*36;
    else if (slot < 8) base = 720 + (slot-4)*36;
    else base = 864 + (slot-8)*36;
    float x0 = raw[r][base + 0*12 + h];
    float x1 = raw[r][base + 1*12 + h];
    float x2 = raw[r][base + 2*12 + h];
    const float* R = rot + (size_t)i*9;
    const float* T = trans + (size_t)i*3;
    float g0 = R[0]*x0 + R[1]*x1 + R[2]*x2 + T[0];
    float g1 = R[3]*x0 + R[4]*x1 + R[5]*x2 + T[1];
    float g2 = R[6]*x0 + R[7]*x1 + R[8]*x2 + T[2];
    gbuf[r][slot][h][0]=g0; gbuf[r][slot][h][1]=g1; gbuf[r][slot][h][2]=g2;
    if (slot < 4) {
      float sc2 = 2.0f*W_L*(gamma[h]*W_C*0.5f);
      float* q = Qt + (size_t)i*384 + h*32 + 16 + slot*3;
      q[0]=sc2*g0; q[1]=sc2*g1; q[2]=sc2*g2;
    } else if (slot < 8) {
      ushort_t* k = Ktb + (size_t)i*384 + h*32 + 16 + (slot-4)*3;
      k[0]=f2bf(g0); k[1]=f2bf(g1); k[2]=f2bf(g2);
    } else {
      ushort_t* vp = vvT + (size_t)(h*40 + 16 + (slot-8)*3)*768 + i;
      vp[0]=f2bf(g0); vp[768]=f2bf(g1); vp[2*768]=f2bf(g2);
    }
  }
  __syncthreads();
  for (int s = tid; s < 96; s += 256) {
    int r = s / 24, rem = s % 24;
    int h = rem / 2, qk = rem % 2;
    int i = i0 + r;
    float sum = 0;
    int b0 = qk ? 4 : 0;
    for (int p = 0; p < 4; ++p)
      for (int t = 0; t < 3; ++t) { float g = gbuf[r][b0+p][h][t]; sum += g*g; }
    float sc = gamma[h]*W_C*0.5f;
    if (qk == 0) {
      float* q = Qt + (size_t)i*384 + h*32;
      q[28] = -W_L*sc; q[29] = -W_L*sc*sum; q[30] = 0.f; q[31] = 0.f;
    } else {
      ushort_t* k = Ktb + (size_t)i*384 + h*32;
      k[28] = f2bf(sum); k[29] = f2bf(1.f); k[30] = 0; k[31] = 0;
    }
  }
}

// ---------------- K2a: logits L[i,h,j] (MFMA, one barrier) --------------
__global__ __launch_bounds__(256) void k2a_logits(
    const float* __restrict__ pair, const float* __restrict__ Wb,
    const float* __restrict__ Qt, const ushort_t* __restrict__ Ktb,
    float* __restrict__ L)
{
  __shared__ ushort_t Tj[64*136];
  __shared__ ushort_t WbT[16*136];
  __shared__ float Qrow[384];
  const int tid = threadIdx.x;
  const int i = blockIdx.x / 12;
  const int j0 = (blockIdx.x % 12) * 64;
  const int lane = tid & 63;
  const int w = tid >> 6;
  const int co = lane & 15, gg = lane >> 4;

  for (int s = tid; s < 1536; s += 256) {
    int z = s / 12, h = s % 12;
    WbT[h*136 + z] = f2bf(W_L * Wb[s]);
  }
  for (int s = tid; s < 544; s += 256) WbT[1632 + s] = 0;
  for (int s = tid; s < 384; s += 256) Qrow[s] = Qt[(size_t)i*384 + s];

  const float* src = pair + ((size_t)i*NN + j0)*128;
  #pragma unroll
  for (int k = 0; k < 8; ++k) {
    int f = tid + k*256;
    int row = f >> 5, zq = f & 31;
    float4 v = *(const float4*)(src + (size_t)row*128 + zq*4);
    uint_t u0 = ((uint_t)f2bf(v.y) << 16) | f2bf(v.x);
    uint_t u1 = ((uint_t)f2bf(v.w) << 16) | f2bf(v.z);
    uint_t* d = (uint_t*)&Tj[row*136 + zq*4];
    d[0] = u0; d[1] = u1;
  }
  __syncthreads();

  short8 z8, myQ, wb[4];
  #pragma unroll
  for (int s = 0; s < 8; ++s) z8[s] = 0;
  #pragma unroll
  for (int s = 0; s < 8; ++s)
    myQ[s] = (co < 12) ? (short)f2bf(Qrow[co*32 + gg*8 + s]) : (short)0;
  #pragma unroll
  for (int kt = 0; kt < 4; ++kt)
    wb[kt] = *(const short8*)&WbT[co*136 + kt*32 + gg*8];

  const int jb = w*16;
  floatx4 D; D[0]=0.f; D[1]=0.f; D[2]=0.f; D[3]=0.f;
  #pragma unroll
  for (int kt = 0; kt < 4; ++kt) {
    short8 a = *(const short8*)&Tj[(jb+co)*136 + kt*32 + gg*8];
    D = __builtin_amdgcn_mfma_f32_16x16x32_bf16(a, wb[kt], D, 0, 0, 0);
  }
  const ushort_t* kr = Ktb + (size_t)(j0 + jb + co)*384;
  #pragma unroll
  for (int kt = 0; kt < 12; ++kt) {
    short8 a = *(const short8*)(kr + kt*32 + gg*8);
    short8 b = (co == kt) ? myQ : z8;
    D = __builtin_amdgcn_mfma_f32_16x16x32_bf16(a, b, D, 0, 0, 0);
  }
  if (co < 12) {
    float4 st = {D[0], D[1], D[2], D[3]};
    *(float4*)(L + ((size_t)i*12 + co)*768 + j0 + jb + gg*4) = st;
  }
}

// ---------------- K3: fused softmax + out_pair + value/points (MFMA) ----
__global__ __launch_bounds__(512) void k3_fused(
    const float* __restrict__ pair, const float* __restrict__ L,
    const ushort_t* __restrict__ vvT, const float* __restrict__ rot,
    const float* __restrict__ trans, float* __restrict__ C2)
{
  __shared__ ushort_t PTb[24*512];        // [t][h16][j32] bf16 a
  __shared__ ushort_t Tz[2][2][128*20];   // [buf][jhalf][z][16+4pad] swizzled
  __shared__ float oacc[480];
  const int tid = threadIdx.x;
  const int i = (NN - 1) - blockIdx.x;    // reverse for L3 reuse
  const int w = tid >> 6, lane = tid & 63;
  const int co = lane & 15, gg = lane >> 4;

  const float* psrc = pair + (size_t)i*NN*128;

  // prefetch tile 0 (overlaps softmax)
  float4 pr0, pr1;
  {
    int f0 = tid,      j0 = f0 >> 5, zq0 = f0 & 31;
    int f1 = tid + 512, j1 = f1 >> 5, zq1 = f1 & 31;
    pr0 = *(const float4*)(psrc + (size_t)j0*128 + zq0*4);
    pr1 = *(const float4*)(psrc + (size_t)j1*128 + zq1*4);
  }

  // ---- softmax from L -> PTb (bf16) ----
  const float* Lr = L + (size_t)i*12*768;
  #pragma unroll
  for (int m = 0; m < 2; ++m) {
    if (m == 1 && w >= 4) break;
    const int h = (m == 0) ? w : 8 + w;
    const float* row = Lr + (size_t)h*768;
    float mx = -1e30f;
    #pragma unroll
    for (int k = 0; k < 12; ++k) mx = fmaxf(mx, row[lane + 64*k]);
    mx = wave_max(mx);
    float ev[12]; float sm = 0.f;
    #pragma unroll
    for (int k = 0; k < 12; ++k) { ev[k] = __expf(row[lane + 64*k] - mx); sm += ev[k]; }
    sm = wave_sum(sm);
    const float inv = 1.0f / sm;
    #pragma unroll
    for (int k = 0; k < 12; ++k) {
      int jj = lane + 64*k;
      PTb[(jj >> 5)*512 + h*32 + (jj & 31)] = f2bf(ev[k]*inv);
    }
  }
  for (int s = tid; s < 3072; s += 512) {
    int t = s >> 7, rest = s & 127;
    PTb[t*512 + 384 + rest] = 0;   // zero h=12..15 rows
  }

  floatx4 accZ; accZ[0]=0.f; accZ[1]=0.f; accZ[2]=0.f; accZ[3]=0.f;
  floatx4 accV[4];
  #pragma unroll
  for (int u = 0; u < 4; ++u) { accV[u][0]=0.f; accV[u][1]=0.f; accV[u][2]=0.f; accV[u][3]=0.f; }

  const int sw = (w & 3) << 2;           // read-side XOR (z>>4 == w for co<16)
  const int jb = (gg & 1) * 8;
  const ushort_t* vb0 = vvT + (size_t)((w*4+0)*16 + co)*768 + gg*8;
  const ushort_t* vb1 = vvT + (size_t)((w*4+1)*16 + co)*768 + gg*8;
  const ushort_t* vb2 = vvT + (size_t)((w*4+2)*16 + co)*768 + gg*8;
  const ushort_t* vb3 = vvT + (size_t)((w*4+3)*16 + co)*768 + gg*8;

  #pragma unroll 1
  for (int t = 0; t < 24; ++t) {
    const int buf = t & 1;
    // stage pr -> Tz (z-major, split-half + XOR swizzle)
    {
      int f0 = tid,      j0 = f0 >> 5, zq0 = f0 & 31;
      int f1 = tid + 512, j1 = f1 >> 5, zq1 = f1 & 31;
      const float* p0 = (const float*)&pr0;
      const float* p1 = (const float*)&pr1;
      ushort_t* tz0 = &Tz[buf][j0 >> 4][0];
      ushort_t* tz1 = &Tz[buf][j1 >> 4][0];
      const int jl0 = j0 & 15, jl1 = j1 & 15;
      #pragma unroll
      for (int e = 0; e < 4; ++e) {
        int z0 = zq0*4 + e;
        tz0[z0*20 + (jl0 ^ (((z0 >> 4) & 3) << 2))] = f2bf(p0[e]);
        int z1 = zq1*4 + e;
        tz1[z1*20 + (jl1 ^ (((z1 >> 4) & 3) << 2))] = f2bf(p1[e]);
      }
    }
    // prefetch t+1
    if (t < 23) {
      const float* sn = psrc + (size_t)(t+1)*32*128;
      int f0 = tid,      j0 = f0 >> 5, zq0 = f0 & 31;
      int f1 = tid + 512, j1 = f1 >> 5, zq1 = f1 & 31;
      pr0 = *(const float4*)(sn + (size_t)j0*128 + zq0*4);
      pr1 = *(const float4*)(sn + (size_t)j1*128 + zq1*4);
    }
    __syncthreads();

    const short8 aP = *(const short8*)&PTb[t*512 + co*32 + gg*8];
    // pair MFMA: wave w owns z-block n=w
    {
      const ushort_t* tz = &Tz[buf][gg >> 1][0];
      const int zrow = (w*16 + co)*20;
      short4_t lo = *(const short4_t*)&tz[zrow + (jb ^ sw)];
      short4_t hi = *(const short4_t*)&tz[zrow + ((jb + 4) ^ sw)];
      short8 bT;
      #pragma unroll
      for (int e = 0; e < 4; ++e) { bT[e] = lo[e]; bT[e+4] = hi[e]; }
      accZ = __builtin_amdgcn_mfma_f32_16x16x32_bf16(aP, bT, accZ, 0, 0, 0);
    }
    // vv MFMAs: wave w owns c-blocks w*4 .. w*4+3 (skip >=30)
    {
      const int toff = t*32;
      short8 bV;
      bV = *(const short8*)(vb0 + toff);
      accV[0] = __builtin_amdgcn_mfma_f32_16x16x32_bf16(aP, bV, accV[0], 0, 0, 0);
      bV = *(const short8*)(vb1 + toff);
      accV[1] = __builtin_amdgcn_mfma_f32_16x16x32_bf16(aP, bV, accV[1], 0, 0, 0);
      if (w*4 + 2 < 30) {
        bV = *(const short8*)(vb2 + toff);
        accV[2] = __builtin_amdgcn_mfma_f32_16x16x32_bf16(aP, bV, accV[2], 0, 0, 0);
        bV = *(const short8*)(vb3 + toff);
        accV[3] = __builtin_amdgcn_mfma_f32_16x16x32_bf16(aP, bV, accV[3], 0, 0, 0);
      }
    }
  }

  // ---- epilogue ----
  float* o = C2 + (size_t)i*2112;
  #pragma unroll
  for (int r = 0; r < 4; ++r) {
    int h = gg*4 + r;
    if (h < 12) o[(w*16 + co)*12 + h] = accZ[r];
  }
  #pragma unroll
  for (int u = 0; u < 4; ++u) {
    int cb = w*4 + u;
    if (cb < 30) {
      int c = cb*16 + co;
      int hc = c / 40;
      #pragma unroll
      for (int r = 0; r < 4; ++r)
        if (gg*4 + r == hc) oacc[c] = accV[u][r];
    }
  }
  __syncthreads();

  if (tid < 96) {
    const int pp = tid / 12, hh = tid % 12;
    const float* R = rot + (size_t)i*9;
    const float* T = trans + (size_t)i*3;
    float x0 = oacc[hh*40+16+pp*3+0] - T[0];
    float x1 = oacc[hh*40+16+pp*3+1] - T[1];
    float x2 = oacc[hh*40+16+pp*3+2] - T[2];
    float y0 = R[0]*x0 + R[3]*x1 + R[6]*x2;
    float y1 = R[1]*x0 + R[4]*x1 + R[7]*x2;
    float y2 = R[2]*x0 + R[5]*x1 + R[8]*x2;
    o[1728 + pp*36 + hh*3 + 0] = y0;
    o[1728 + pp*36 + hh*3 + 1] = y1;
    o[1728 + pp*36 + hh*3 + 2] = y2;
    o[2016 + pp*12 + hh] = sqrtf(y0*y0 + y1*y1 + y2*y2);
  } else if (tid < 288) {
    const int c = tid - 96;
    int d = c / 12, hh = c % 12;
    o[1536 + d*12 + hh] = oacc[hh*40 + d];
  }
}

// ---------------- K5: final GEMM 768x2112 @ 2112x384 + bias -------------
__global__ __launch_bounds__(256) void k5_out(
    const float* __restrict__ C2, const float* __restrict__ Wout,
    const float* __restrict__ bout, float* __restrict__ out)
{
  __shared__ float Al[32*68];
  __shared__ float Bl[64*36];
  const int tid = threadIdx.x;
  const int bm = blockIdx.x / 12, bn = blockIdx.x % 12;
  const int tr = tid / 16, tc = tid % 16;
  float acc00=0, acc01=0, acc10=0, acc11=0;
  for (int kc = 0; kc < 33; ++kc) {
    __syncthreads();
    for (int s = tid; s < 512; s += 256) {
      int row = s / 16, kq = s % 16;
      *(float4*)(&Al[row*68 + kq*4]) =
        *(const float4*)(C2 + (size_t)(bm*32+row)*2112 + kc*64 + kq*4);
    }
    for (int s = tid; s < 512; s += 256) {
      int kk = s / 8, cq = s % 8;
      *(float4*)(&Bl[kk*36 + cq*4]) =
        *(const float4*)(Wout + (size_t)(kc*64+kk)*384 + bn*32 + cq*4);
    }
    __syncthreads();
    for (int kk = 0; kk < 64; ++kk) {
      float a0 = Al[(tr*2)*68 + kk], a1 = Al[(tr*2+1)*68 + kk];
      float b0 = Bl[kk*36 + tc*2], b1 = Bl[kk*36 + tc*2 + 1];
      acc00 += a0*b0; acc01 += a0*b1;
      acc10 += a1*b0; acc11 += a1*b1;
    }
  }
  int r0 = bm*32 + tr*2, c0 = bn*32 + tc*2;
  out[(size_t)r0*384 + c0]       = acc00 + bout[c0];
  out[(size_t)r0*384 + c0+1]     = acc01 + bout[c0+1];
  out[(size_t)(r0+1)*384 + c0]   = acc10 + bout[c0];
  out[(size_t)(r0+1)*384 + c0+1] = acc11 + bout[c0+1];
}

extern "C" void kernel_launch(void* const* d_in, const int* in_sizes, int n_in,
                              void* d_out, int out_size, void* d_ws, size_t ws_size,
                              hipStream_t stream)
{
  const float* single = (const float*)d_in[0];
  const float* pair   = (const float*)d_in[1];
  const float* rot    = (const float*)d_in[2];
  const float* trans  = (const float*)d_in[3];
  const float* Wqkv   = (const float*)d_in[4];
  const float* Wb     = (const float*)d_in[5];
  const float* Wqk    = (const float*)d_in[6];
  const float* Wvp    = (const float*)d_in[7];
  const float* gamma  = (const float*)d_in[8];
  const float* Wout   = (const float*)d_in[9];
  const float* bout   = (const float*)d_in[10];

  float* ws   = (float*)d_ws;
  float* raw  = ws;                                   // 768*1152
  float* Qt   = raw + (size_t)768*1152;               // 768*384
  float* C2   = Qt  + (size_t)768*384;                // 768*2112
  float* L    = C2  + (size_t)768*2112;               // 768*12*768
  ushort_t* Ktb = (ushort_t*)(L + (size_t)768*12*768); // 768*384 bf16
  ushort_t* vvT = Ktb + (size_t)768*384;               // 480*768 bf16
  float* out  = (float*)d_out;

  k1a_gemm<<<dim3(216), dim3(256), 0, stream>>>(single, Wqkv, Wqk, Wvp, raw);
  k1b_pack<<<dim3(192), dim3(256), 0, stream>>>(raw, rot, trans, gamma, Qt, Ktb, vvT);
  k2a_logits<<<dim3(9216), dim3(256), 0, stream>>>(pair, Wb, Qt, Ktb, L);
  k3_fused<<<dim3(768), dim3(512), 0, stream>>>(pair, L, vvT, rot, trans, C2);
  k5_out<<<dim3(288), dim3(256), 0, stream>>>(C2, Wout, bout, out);
}